// Round 3
// baseline (383.955 us; speedup 1.0000x reference)
//
#include <hip/hip_runtime.h>
#include <hip/hip_bf16.h>
#include <stdint.h>

typedef short bf16x8 __attribute__((ext_vector_type(8)));
typedef float f32x16 __attribute__((ext_vector_type(16)));

#define T 2048
#define KLEN 2049
#define DK 32
#define NCO 32
#define NCI 32
#define NB 32

#define GR 2120          // padded reversed row length
#define SREF 2055        // x[s] lives at g = SREF - s  (xr); xrs holds value at g+1
#define WT_CH 257        // 8-wide d-chunks, d in [0,2056)
#define WT_ELEMS (NCI*WT_CH*NCO*8)
#define XR_ELEMS (NB*NCI*GR)

#define WT_OFF 0
#define XR_OFF (WT_ELEMS*2)
#define XRS_OFF (XR_OFF + XR_ELEMS*2)

#define CIB 208          // bytes per ci row (13 x 16B granules)
#define CPYB 6720        // parity-copy stride: 32*208=6656 +64B pad (bank de-alias)
#define SECB (2*CPYB)    // per (tile,b) section: 13440 B
// sections: sec = tb*2 + bs  (tb: 0=tileA 1=tileB, bs: b-select)

// ---------------- kernel-generation: SIREN -> flipped, fragment-layout W ----
__global__ __launch_bounds__(256) void gen_w(
    const float* __restrict__ rel_pos,
    const float* __restrict__ w1, const float* __restrict__ b1, const float* __restrict__ om1,
    const float* __restrict__ w2, const float* __restrict__ b2, const float* __restrict__ om2,
    const float* __restrict__ w3, const float* __restrict__ b3,
    uint16_t* __restrict__ Wt)
{
    int d = blockIdx.x;          // flipped lag, 0..2055
    int tid = threadIdx.x;
    if (d >= KLEN) {             // zero pad region
        for (int r = 0; r < 4; ++r) {
            int coci = tid + 256*r;
            int co = coci >> 5, ci = coci & 31;
            Wt[(((ci*WT_CH + (d>>3))*NCO + co)<<3) + (d&7)] = 0;
        }
        return;
    }
    int kk = 2048 - d;
    float pos = rel_pos[kk];
    __shared__ float h1[DK];
    __shared__ float h2[DK];
    if (tid < DK) h1[tid] = sinf(om1[0]*(w1[tid]*pos + b1[tid]));
    __syncthreads();
    if (tid < DK) {
        float a = b2[tid];
        for (int j = 0; j < DK; ++j) a += w2[tid*DK+j]*h1[j];
        h2[tid] = sinf(om2[0]*a);
    }
    __syncthreads();
    for (int r = 0; r < 4; ++r) {
        int coci = tid + 256*r;
        float a = b3[coci];
        for (int j = 0; j < DK; ++j) a += w3[coci*DK+j]*h2[j];
        int co = coci >> 5, ci = coci & 31;
        __hip_bfloat16 hv = __float2bfloat16(a);
        Wt[(((ci*WT_CH + (d>>3))*NCO + co)<<3) + (d&7)] = *(uint16_t*)&hv;
    }
}

// ---------------- x -> reversed, zero-padded bf16 (plus shifted copy) -------
__global__ __launch_bounds__(256) void gen_x(const float* __restrict__ x,
                                             uint16_t* __restrict__ xr,
                                             uint16_t* __restrict__ xrs)
{
    int idx = blockIdx.x*256 + threadIdx.x;
    if (idx >= NB*NCI*GR) return;
    int row = idx / GR;          // b*32+ci
    int g = idx - row*GR;
    int s = SREF - g;
    float v  = (s  >= 0 && s  < T) ? x[row*T + s]  : 0.f;
    int s2 = s - 1;              // value at g+1
    float v2 = (s2 >= 0 && s2 < T) ? x[row*T + s2] : 0.f;
    __hip_bfloat16 hv = __float2bfloat16(v);
    __hip_bfloat16 hv2 = __float2bfloat16(v2);
    xr[idx]  = *(uint16_t*)&hv;
    xrs[idx] = *(uint16_t*)&hv2;
}

// ---------------- causal conv as implicit-Toeplitz MFMA GEMM ----------------
// Block = (b-pair bg, pair pr): 512 thr / 8 waves. tileA = t-tile (63-pr),
// tileB = t-tile pr (32 t's each), b in {2bg, 2bg+1}. Uniform 33 window-tiles.
// Wave w: bs = w&1 (b-select), cig = w>>1 (ci mod 4). 4 acc chains per wave.
__global__ __launch_bounds__(512, 4) void conv(
    const uint16_t* __restrict__ Wt, const uint16_t* __restrict__ xr,
    const uint16_t* __restrict__ xrs,
    const float* __restrict__ bias, float* __restrict__ out)
{
    __shared__ uint4 lds4[4*SECB/16];   // 53760 B; reduce area reuses first 32KB
    char* lds = (char*)lds4;
    int tid = threadIdx.x;
    int pr = blockIdx.x & 31;
    int b0 = (blockIdx.x >> 5) << 1;
    int ttA = 63 - pr, ttB = pr;
    int t0A = ttA << 5, t0B = ttB << 5;
    int nwA = (ttA >> 1) + 1;
    int nwB = (ttB >> 1) + 1;
    int w = tid >> 6, lane = tid & 63, n = lane & 31, hi = lane >> 5;
    int bs = w & 1, cig = w >> 1;

    f32x16 aA0, aA1, aB0, aB1;
    #pragma unroll
    for (int r = 0; r < 16; ++r) { aA0[r] = 0.f; aA1[r] = 0.f; aB0[r] = 0.f; aB1[r] = 0.f; }

    for (int wi = 0; wi < nwA; ++wi) {
        int actB = (wi < nwB);
        int g0A = 2016 - t0A + (wi << 6);   // multiple of 8
        int g0B = 2016 - t0B + (wi << 6);
        // stage: per active section, 2 parity copies x 32 ci x 13 16B-granules
        int ng = actB ? 3328 : 1664;
        for (int gi = tid; gi < ng; gi += 512) {
            int sec = (gi >= 1664) ? ((gi >= 2496) ? 3 : 2) : ((gi >= 832) ? 1 : 0);
            int r = gi - sec*832;
            int tb = sec >> 1, bsec = sec & 1;
            int cpy = r >= 416;
            int g3 = r - (cpy ? 416 : 0);
            int ci = (g3 * 5042) >> 16;     // g3/13 for g3<416
            int q  = g3 - ci*13;
            int g0 = tb ? g0B : g0A;
            const uint16_t* src = (cpy ? xrs : xr) + (((b0 + bsec)*NCI + ci)*GR + g0 + (q<<3));
            char* dst = lds + sec*SECB + cpy*CPYB + ci*CIB + (q<<4);
            *(uint4*)dst = *(const uint4*)src;
        }
        __syncthreads();
        int dcw = (wi << 3);
        const char* baseA = lds + bs*SECB;          // sec = 0*2+bs
        const char* baseB = lds + (2 + bs)*SECB;    // sec = 1*2+bs
        for (int c = 0; c < 4; ++c) {
            int o = 39 - n + (c << 4) + (hi << 3);
            int par = o & 1;
            int boff = par*CPYB + ((o - par) << 1);
            int dc = dcw + (c << 1) + hi;
            #pragma unroll
            for (int cii = 0; cii < 8; ++cii) {
                int ci = (cii << 2) + cig;          // wave-private ci subset
                bf16x8 av = *(const bf16x8*)(Wt + (((ci*WT_CH + dc)*NCO + n) << 3));
                {
                    const char* p = baseA + ci*CIB + boff;
                    union { uint32_t u[4]; bf16x8 v; } bb;
                    bb.u[0] = *(const uint32_t*)(p);
                    bb.u[1] = *(const uint32_t*)(p + 4);
                    bb.u[2] = *(const uint32_t*)(p + 8);
                    bb.u[3] = *(const uint32_t*)(p + 12);
                    if (cii < 4) aA0 = __builtin_amdgcn_mfma_f32_32x32x16_bf16(av, bb.v, aA0, 0, 0, 0);
                    else         aA1 = __builtin_amdgcn_mfma_f32_32x32x16_bf16(av, bb.v, aA1, 0, 0, 0);
                }
                if (actB) {
                    const char* p = baseB + ci*CIB + boff;
                    union { uint32_t u[4]; bf16x8 v; } bb;
                    bb.u[0] = *(const uint32_t*)(p);
                    bb.u[1] = *(const uint32_t*)(p + 4);
                    bb.u[2] = *(const uint32_t*)(p + 8);
                    bb.u[3] = *(const uint32_t*)(p + 12);
                    if (cii < 4) aB0 = __builtin_amdgcn_mfma_f32_32x32x16_bf16(av, bb.v, aB0, 0, 0, 0);
                    else         aB1 = __builtin_amdgcn_mfma_f32_32x32x16_bf16(av, bb.v, aB1, 0, 0, 0);
                }
            }
        }
        __syncthreads();
    }

    f32x16 aA, aB;
    #pragma unroll
    for (int r = 0; r < 16; ++r) { aA[r] = aA0[r] + aA1[r]; aB[r] = aB0[r] + aB1[r]; }

    // cross-wave ci reduction via LDS (per b-select region of 16KB)
    float* red = (float*)lds4;
    // ---- tile A ----
    #pragma unroll
    for (int r = 0; r < 16; ++r)
        red[bs*4096 + (cig*16 + r)*64 + lane] = aA[r];
    __syncthreads();
    for (int e = tid; e < 2048; e += 512) {
        int ebs = e >> 10, e10 = e & 1023;
        int lane_e = e10 & 63;
        int reg = e10 >> 6;
        float s = 0.f;
        #pragma unroll
        for (int cg = 0; cg < 4; ++cg) s += red[ebs*4096 + (cg*16 + reg)*64 + lane_e];
        int co = (reg & 3) + ((reg >> 2) << 3) + ((lane_e >> 5) << 2);
        int t = t0A + (lane_e & 31);
        out[((b0 + ebs)*NCO + co)*T + t] = s + bias[co];
    }
    __syncthreads();
    // ---- tile B ----
    #pragma unroll
    for (int r = 0; r < 16; ++r)
        red[bs*4096 + (cig*16 + r)*64 + lane] = aB[r];
    __syncthreads();
    for (int e = tid; e < 2048; e += 512) {
        int ebs = e >> 10, e10 = e & 1023;
        int lane_e = e10 & 63;
        int reg = e10 >> 6;
        float s = 0.f;
        #pragma unroll
        for (int cg = 0; cg < 4; ++cg) s += red[ebs*4096 + (cg*16 + reg)*64 + lane_e];
        int co = (reg & 3) + ((reg >> 2) << 3) + ((lane_e >> 5) << 2);
        int t = t0B + (lane_e & 31);
        out[((b0 + ebs)*NCO + co)*T + t] = s + bias[co];
    }
}

extern "C" void kernel_launch(void* const* d_in, const int* in_sizes, int n_in,
                              void* d_out, int out_size, void* d_ws, size_t ws_size,
                              hipStream_t stream)
{
    const float* x       = (const float*)d_in[0];
    const float* rel_pos = (const float*)d_in[1];
    const float* w1  = (const float*)d_in[2];
    const float* b1  = (const float*)d_in[3];
    const float* om1 = (const float*)d_in[4];
    const float* w2  = (const float*)d_in[5];
    const float* b2  = (const float*)d_in[6];
    const float* om2 = (const float*)d_in[7];
    const float* w3  = (const float*)d_in[8];
    const float* b3  = (const float*)d_in[9];
    const float* bias = (const float*)d_in[10];
    float* out = (float*)d_out;
    char* ws = (char*)d_ws;
    uint16_t* Wt  = (uint16_t*)(ws + WT_OFF);
    uint16_t* xrp = (uint16_t*)(ws + XR_OFF);
    uint16_t* xrs = (uint16_t*)(ws + XRS_OFF);

    hipLaunchKernelGGL(gen_w, dim3(WT_CH*8), dim3(256), 0, stream,
                       rel_pos, w1, b1, om1, w2, b2, om2, w3, b3, Wt);
    int n2 = NB*NCI*GR;
    hipLaunchKernelGGL(gen_x, dim3((n2+255)/256), dim3(256), 0, stream, x, xrp, xrs);
    hipLaunchKernelGGL(conv, dim3(16*32), dim3(512), 0, stream, Wt, xrp, xrs, bias, out);
}

// Round 4
// 356.302 us; speedup vs baseline: 1.0776x; 1.0776x over previous
//
#include <hip/hip_runtime.h>
#include <hip/hip_bf16.h>
#include <stdint.h>

typedef short bf16x8 __attribute__((ext_vector_type(8)));
typedef float f32x16 __attribute__((ext_vector_type(16)));

#define T 2048
#define KLEN 2049
#define DK 32
#define NCO 32
#define NCI 32
#define NB 32

#define GR 2120          // padded reversed row length
#define SREF 2055        // x[s] lives at g = SREF - s  (xr); xrs holds value at g+1
#define WT_CH 257        // 8-wide d-chunks, d in [0,2056)
#define WT_ELEMS (NCI*WT_CH*NCO*8)
#define XR_ELEMS (NB*NCI*GR)

#define WT_OFF 0
#define XR_OFF (WT_ELEMS*2)
#define XRS_OFF (XR_OFF + XR_ELEMS*2)

#define CIB 208          // bytes per ci row (13 x 16B granules)
#define CPYB 6720        // parity-copy stride: 32*208=6656 +64B pad
#define SECB (2*CPYB)    // per (tile,b) section: 13440 B
#define ASTEP (4*WT_CH*NCO*8)   // A-pointer step per cii (uint16 elements)

// ---------------- kernel-generation: SIREN -> flipped, fragment-layout W ----
__global__ __launch_bounds__(256) void gen_w(
    const float* __restrict__ rel_pos,
    const float* __restrict__ w1, const float* __restrict__ b1, const float* __restrict__ om1,
    const float* __restrict__ w2, const float* __restrict__ b2, const float* __restrict__ om2,
    const float* __restrict__ w3, const float* __restrict__ b3,
    uint16_t* __restrict__ Wt)
{
    int d = blockIdx.x;          // flipped lag, 0..2055
    int tid = threadIdx.x;
    if (d >= KLEN) {             // zero pad region
        for (int r = 0; r < 4; ++r) {
            int coci = tid + 256*r;
            int co = coci >> 5, ci = coci & 31;
            Wt[(((ci*WT_CH + (d>>3))*NCO + co)<<3) + (d&7)] = 0;
        }
        return;
    }
    int kk = 2048 - d;
    float pos = rel_pos[kk];
    __shared__ float h1[DK];
    __shared__ float h2[DK];
    if (tid < DK) h1[tid] = sinf(om1[0]*(w1[tid]*pos + b1[tid]));
    __syncthreads();
    if (tid < DK) {
        float a = b2[tid];
        for (int j = 0; j < DK; ++j) a += w2[tid*DK+j]*h1[j];
        h2[tid] = sinf(om2[0]*a);
    }
    __syncthreads();
    for (int r = 0; r < 4; ++r) {
        int coci = tid + 256*r;
        float a = b3[coci];
        for (int j = 0; j < DK; ++j) a += w3[coci*DK+j]*h2[j];
        int co = coci >> 5, ci = coci & 31;
        __hip_bfloat16 hv = __float2bfloat16(a);
        Wt[(((ci*WT_CH + (d>>3))*NCO + co)<<3) + (d&7)] = *(uint16_t*)&hv;
    }
}

// ---------------- x -> reversed, zero-padded bf16 (plus shifted copy) -------
__global__ __launch_bounds__(256) void gen_x(const float* __restrict__ x,
                                             uint16_t* __restrict__ xr,
                                             uint16_t* __restrict__ xrs)
{
    int idx = blockIdx.x*256 + threadIdx.x;
    if (idx >= NB*NCI*GR) return;
    int row = idx / GR;          // b*32+ci
    int g = idx - row*GR;
    int s = SREF - g;
    float v  = (s  >= 0 && s  < T) ? x[row*T + s]  : 0.f;
    int s2 = s - 1;              // value at g+1
    float v2 = (s2 >= 0 && s2 < T) ? x[row*T + s2] : 0.f;
    __hip_bfloat16 hv = __float2bfloat16(v);
    __hip_bfloat16 hv2 = __float2bfloat16(v2);
    xr[idx]  = *(uint16_t*)&hv;
    xrs[idx] = *(uint16_t*)&hv2;
}

// ---------------- causal conv as implicit-Toeplitz MFMA GEMM ----------------
// Block = (b-pair, tile-pair): 512 thr / 8 waves. Async staging (T14):
// stage loads for wi+1 issued after c=0 A-loads of wi; LDS write after the
// post-compute barrier. A-fragments batch-prefetched per c-iter.
__global__ __launch_bounds__(512, 4) void conv(
    const uint16_t* __restrict__ Wt, const uint16_t* __restrict__ xr,
    const float* __restrict__ bias, float* __restrict__ out)
{
    __shared__ uint4 lds4[4*SECB/16];   // 53760 B; reduce reuses first 32KB
    char* lds = (char*)lds4;
    int tid = threadIdx.x;
    int pr = blockIdx.x & 31;
    int b0 = (blockIdx.x >> 5) << 1;
    int ttA = 63 - pr, ttB = pr;
    int t0A = ttA << 5, t0B = ttB << 5;
    int nwA = (ttA >> 1) + 1;
    int nwB = (ttB >> 1) + 1;
    int w = tid >> 6, lane = tid & 63, n = lane & 31, hi = lane >> 5;
    int bs = w & 1, cig = w >> 1;

    // ---- hoisted staging descriptors (window-invariant) ----
    int sOff[7], sDst[7];
    #pragma unroll
    for (int k = 0; k < 7; ++k) {
        int gi = tid + (k << 9);
        if (gi < 3328) {
            int sec = (gi >= 1664) ? ((gi >= 2496) ? 3 : 2) : ((gi >= 832) ? 1 : 0);
            int r = gi - sec*832;
            int bsec = sec & 1;
            int cpy = r >= 416;
            int g3 = r - (cpy ? 416 : 0);
            int ci = (g3 * 5042) >> 16;     // g3/13 for g3<416
            int q  = g3 - ci*13;
            sOff[k] = (cpy ? XR_ELEMS : 0) + ((b0 + bsec)*NCI + ci)*GR + (q<<3);
            sDst[k] = sec*SECB + cpy*CPYB + ci*CIB + (q<<4);
        } else { sOff[k] = -1; sDst[k] = 0; }
    }

    // ---- block-invariant B-read offsets per c ----
    int bAoff[4];
    #pragma unroll
    for (int c = 0; c < 4; ++c) {
        int o = 39 - n + (c << 4) + (hi << 3);
        int par = o & 1;
        bAoff[c] = bs*SECB + cig*CIB + par*CPYB + ((o - par) << 1);
    }

    f32x16 aA, aB;
    #pragma unroll
    for (int r = 0; r < 16; ++r) { aA[r] = 0.f; aB[r] = 0.f; }

    uint4 vals[7];

    // ---- prologue: stage window 0 (both tiles; nwB >= 1 always) ----
    {
        int g0A_e = 2016 - t0A;
        int g0B_e = 2016 - t0B;
        #pragma unroll
        for (int k = 0; k < 7; ++k) {
            if (sOff[k] >= 0) {
                int g = (sDst[k] >= 2*SECB) ? g0B_e : g0A_e;
                vals[k] = *(const uint4*)(xr + sOff[k] + g);
            }
        }
        #pragma unroll
        for (int k = 0; k < 7; ++k)
            if (sOff[k] >= 0) *(uint4*)(lds + sDst[k]) = vals[k];
        __syncthreads();
    }

    const uint16_t* aCol = Wt + ((cig*WT_CH + hi)*NCO + n)*8;  // + dcw*NCO*8 per wi

    for (int wi = 0; wi < nwA; ++wi) {
        int actB = (wi < nwB);
        const uint16_t* aBase = aCol + (wi << 3)*NCO*8;
        int havN = (wi + 1 < nwA);
        int actBn = (wi + 1 < nwB);

        bf16x8 av[8];
        // ---- c = 0: A-issue, then stage-issue for wi+1, then compute ----
        #pragma unroll
        for (int cii = 0; cii < 8; ++cii)
            av[cii] = *(const bf16x8*)(aBase + cii*ASTEP);

        if (havN) {
            int g0A_e = 2016 - t0A + ((wi + 1) << 6);
            int g0B_e = 2016 - t0B + ((wi + 1) << 6);
            #pragma unroll
            for (int k = 0; k < 7; ++k) {
                int isB = (sDst[k] >= 2*SECB);
                if (sOff[k] >= 0 && (!isB || actBn))
                    vals[k] = *(const uint4*)(xr + sOff[k] + (isB ? g0B_e : g0A_e));
            }
        }

        #pragma unroll
        for (int c = 0; c < 4; ++c) {
            if (c > 0) {
                const uint16_t* aC = aBase + c*(2*NCO*8);
                #pragma unroll
                for (int cii = 0; cii < 8; ++cii)
                    av[cii] = *(const bf16x8*)(aC + cii*ASTEP);
            }
            int offA = bAoff[c];
            #pragma unroll
            for (int cii = 0; cii < 8; ++cii) {
                const char* pA = lds + offA + cii*(4*CIB);
                union { uint32_t u[4]; bf16x8 v; } bb;
                bb.u[0] = *(const uint32_t*)(pA);
                bb.u[1] = *(const uint32_t*)(pA + 4);
                bb.u[2] = *(const uint32_t*)(pA + 8);
                bb.u[3] = *(const uint32_t*)(pA + 12);
                aA = __builtin_amdgcn_mfma_f32_32x32x16_bf16(av[cii], bb.v, aA, 0, 0, 0);
                if (actB) {
                    const char* pB = pA + 2*SECB;
                    union { uint32_t u[4]; bf16x8 v; } b2;
                    b2.u[0] = *(const uint32_t*)(pB);
                    b2.u[1] = *(const uint32_t*)(pB + 4);
                    b2.u[2] = *(const uint32_t*)(pB + 8);
                    b2.u[3] = *(const uint32_t*)(pB + 12);
                    aB = __builtin_amdgcn_mfma_f32_32x32x16_bf16(av[cii], b2.v, aB, 0, 0, 0);
                }
            }
        }
        __syncthreads();
        if (havN) {
            #pragma unroll
            for (int k = 0; k < 7; ++k) {
                int isB = (sDst[k] >= 2*SECB);
                if (sOff[k] >= 0 && (!isB || actBn))
                    *(uint4*)(lds + sDst[k]) = vals[k];
            }
        }
        __syncthreads();
    }

    // cross-wave ci reduction via LDS (per b-select region of 16KB)
    float* red = (float*)lds4;
    // ---- tile A ----
    #pragma unroll
    for (int r = 0; r < 16; ++r)
        red[bs*4096 + (cig*16 + r)*64 + lane] = aA[r];
    __syncthreads();
    for (int e = tid; e < 2048; e += 512) {
        int ebs = e >> 10, e10 = e & 1023;
        int lane_e = e10 & 63;
        int reg = e10 >> 6;
        float s = 0.f;
        #pragma unroll
        for (int cg = 0; cg < 4; ++cg) s += red[ebs*4096 + (cg*16 + reg)*64 + lane_e];
        int co = (reg & 3) + ((reg >> 2) << 3) + ((lane_e >> 5) << 2);
        int t = t0A + (lane_e & 31);
        out[((b0 + ebs)*NCO + co)*T + t] = s + bias[co];
    }
    __syncthreads();
    // ---- tile B ----
    #pragma unroll
    for (int r = 0; r < 16; ++r)
        red[bs*4096 + (cig*16 + r)*64 + lane] = aB[r];
    __syncthreads();
    for (int e = tid; e < 2048; e += 512) {
        int ebs = e >> 10, e10 = e & 1023;
        int lane_e = e10 & 63;
        int reg = e10 >> 6;
        float s = 0.f;
        #pragma unroll
        for (int cg = 0; cg < 4; ++cg) s += red[ebs*4096 + (cg*16 + reg)*64 + lane_e];
        int co = (reg & 3) + ((reg >> 2) << 3) + ((lane_e >> 5) << 2);
        int t = t0B + (lane_e & 31);
        out[((b0 + ebs)*NCO + co)*T + t] = s + bias[co];
    }
}

extern "C" void kernel_launch(void* const* d_in, const int* in_sizes, int n_in,
                              void* d_out, int out_size, void* d_ws, size_t ws_size,
                              hipStream_t stream)
{
    const float* x       = (const float*)d_in[0];
    const float* rel_pos = (const float*)d_in[1];
    const float* w1  = (const float*)d_in[2];
    const float* b1  = (const float*)d_in[3];
    const float* om1 = (const float*)d_in[4];
    const float* w2  = (const float*)d_in[5];
    const float* b2  = (const float*)d_in[6];
    const float* om2 = (const float*)d_in[7];
    const float* w3  = (const float*)d_in[8];
    const float* b3  = (const float*)d_in[9];
    const float* bias = (const float*)d_in[10];
    float* out = (float*)d_out;
    char* ws = (char*)d_ws;
    uint16_t* Wt  = (uint16_t*)(ws + WT_OFF);
    uint16_t* xrp = (uint16_t*)(ws + XR_OFF);
    uint16_t* xrs = (uint16_t*)(ws + XRS_OFF);

    hipLaunchKernelGGL(gen_w, dim3(WT_CH*8), dim3(256), 0, stream,
                       rel_pos, w1, b1, om1, w2, b2, om2, w3, b3, Wt);
    int n2 = NB*NCI*GR;
    hipLaunchKernelGGL(gen_x, dim3((n2+255)/256), dim3(256), 0, stream, x, xrp, xrs);
    hipLaunchKernelGGL(conv, dim3(16*32), dim3(512), 0, stream, Wt, xrp, bias, out);
}

// Round 6
// 230.316 us; speedup vs baseline: 1.6671x; 1.5470x over previous
//
#include <hip/hip_runtime.h>
#include <hip/hip_bf16.h>
#include <stdint.h>

typedef short bf16x8 __attribute__((ext_vector_type(8)));
typedef float f32x16 __attribute__((ext_vector_type(16)));

#define T 2048
#define KLEN 2049
#define DK 32
#define NCO 32
#define NCI 32
#define NB 32

#define GR 2216          // padded reversed row length (widened for K=4 chain window)
#define SREF 2055        // x[s] lives at g = SREF - s (xr); xrs[g] = xr[g+1]
#define WT_CH 257        // 8-wide d-chunks, d in [0,2056)
#define WT_ELEMS (NCI*WT_CH*NCO*8)
#define XR_ELEMS (NB*NCI*GR)

#define WT_OFF 0
#define XR_OFF (WT_ELEMS*2)
#define XRS_OFF (XR_OFF + XR_ELEMS*2)

#define CIB 400          // bytes per ci row: 25 x 16B granules (200 elems)
#define CPYB (NCI*CIB)   // 12800 per parity copy
#define LDSB (2*CPYB)    // 25600 staged total

// ---------------- kernel-generation: SIREN -> flipped, fragment-layout W ----
__global__ __launch_bounds__(256) void gen_w(
    const float* __restrict__ rel_pos,
    const float* __restrict__ w1, const float* __restrict__ b1, const float* __restrict__ om1,
    const float* __restrict__ w2, const float* __restrict__ b2, const float* __restrict__ om2,
    const float* __restrict__ w3, const float* __restrict__ b3,
    uint16_t* __restrict__ Wt)
{
    int d = blockIdx.x;          // flipped lag, 0..2055
    int tid = threadIdx.x;
    if (d >= KLEN) {             // zero pad region
        for (int r = 0; r < 4; ++r) {
            int coci = tid + 256*r;
            int co = coci >> 5, ci = coci & 31;
            Wt[(((ci*WT_CH + (d>>3))*NCO + co)<<3) + (d&7)] = 0;
        }
        return;
    }
    int kk = 2048 - d;
    float pos = rel_pos[kk];
    __shared__ float h1[DK];
    __shared__ float h2[DK];
    if (tid < DK) h1[tid] = sinf(om1[0]*(w1[tid]*pos + b1[tid]));
    __syncthreads();
    if (tid < DK) {
        float a = b2[tid];
        for (int j = 0; j < DK; ++j) a += w2[tid*DK+j]*h1[j];
        h2[tid] = sinf(om2[0]*a);
    }
    __syncthreads();
    for (int r = 0; r < 4; ++r) {
        int coci = tid + 256*r;
        float a = b3[coci];
        for (int j = 0; j < DK; ++j) a += w3[coci*DK+j]*h2[j];
        int co = coci >> 5, ci = coci & 31;
        __hip_bfloat16 hv = __float2bfloat16(a);
        Wt[(((ci*WT_CH + (d>>3))*NCO + co)<<3) + (d&7)] = *(uint16_t*)&hv;
    }
}

// ---------------- x -> reversed, zero-padded bf16 (plus shifted copy) -------
__global__ __launch_bounds__(256) void gen_x(const float* __restrict__ x,
                                             uint16_t* __restrict__ xr,
                                             uint16_t* __restrict__ xrs)
{
    int idx = blockIdx.x*256 + threadIdx.x;
    if (idx >= NB*NCI*GR) return;
    int row = idx / GR;          // b*32+ci
    int g = idx - row*GR;
    int s = SREF - g;
    float v  = (s  >= 0 && s  < T) ? x[row*T + s]  : 0.f;
    int s2 = s - 1;              // value at g+1
    float v2 = (s2 >= 0 && s2 < T) ? x[row*T + s2] : 0.f;
    __hip_bfloat16 hv = __float2bfloat16(v);
    __hip_bfloat16 hv2 = __float2bfloat16(v2);
    xr[idx]  = *(uint16_t*)&hv;
    xrs[idx] = *(uint16_t*)&hv2;
}

// ---------------- causal conv: implicit-Toeplitz MFMA GEMM, K=4 tau-chain ---
// Block = (b, pair p). Phase A: chain {4p..4p+3} (top th=4p+3); phase B: chain
// {60-4p..63-4p} (top th=63-4p). One staged window (200 elems, 2 parity copies)
// serves all 4 taus: bb at element offset obase + 16*(c + 2*delta); av[c]
// reused by up to 4 MFMAs. 8 waves = 8 ci-groups (4 ci each), LDS ci-reduce.
__global__ __launch_bounds__(512, 4) void conv(
    const uint16_t* __restrict__ Wt, const uint16_t* __restrict__ xr,
    const uint16_t* __restrict__ xrs,
    const float* __restrict__ bias, float* __restrict__ out)
{
    __shared__ uint4 lds4[LDSB/16];   // 25600 B staged; reduce reuses 16KB
    char* ldsb = (char*)lds4;
    int tid = threadIdx.x;
    int p = blockIdx.x & 7;
    int b = blockIdx.x >> 3;
    int w = tid >> 6, lane = tid & 63, n = lane & 31, hi = lane >> 5;
    int cig = w;

    // staging descriptors (4 granule-slots per thread, window-invariant parts)
    int sSrc[4], sDst[4];
    #pragma unroll
    for (int k = 0; k < 4; ++k) {
        int gi = tid + (k << 9);
        if (gi < 1600) {
            int cpy = gi >= 800;
            int g3 = cpy ? gi - 800 : gi;
            int ci = (g3 * 2622) >> 16;      // g3/25 for g3<800
            int q  = g3 - ci*25;
            sSrc[k] = (cpy ? XR_ELEMS : 0) + (b*NCI + ci)*GR + (q<<3);
            sDst[k] = cpy*CPYB + ci*CIB + (q<<4);
        } else { sSrc[k] = -1; sDst[k] = 0; }
    }

    // B-read base: o_m = (39 - n + 8*hi) + 16*(c+2d); byte = ci*CIB + par*CPYB + 2*(o-par)
    int obase = 39 - n + (hi << 3);
    int par = obase & 1;
    int bbb = cig*CIB + par*CPYB + ((obase - par) << 1);   // ci row for cii=0

    for (int phase = 0; phase < 2; ++phase) {
        int th = phase ? (63 - (p << 2)) : ((p << 2) + 3);   // odd
        int u = (th - 1) >> 1;                               // windows = u+1

        f32x16 acc0, acc1, acc2, acc3;
        #pragma unroll
        for (int r = 0; r < 16; ++r) { acc0[r]=0.f; acc1[r]=0.f; acc2[r]=0.f; acc3[r]=0.f; }

        for (int wi = 0; wi <= u; ++wi) {
            int g0 = 2016 - (th << 5) + (wi << 6);
            __syncthreads();                 // staged region free (prev window read)
            #pragma unroll
            for (int k = 0; k < 4; ++k) {
                if (sSrc[k] >= 0)
                    *(uint4*)(ldsb + sDst[k]) = *(const uint4*)(xr + sSrc[k] + g0);
            }
            __syncthreads();

            bool full = (wi < u);            // deltas 2,3 inactive on last window
            int dcw = wi << 3;

            #pragma unroll
            for (int cii = 0; cii < 4; ++cii) {
                int ci = (cii << 3) + cig;
                const uint16_t* aB = Wt + (((ci*WT_CH + dcw + hi)*NCO + n) << 3);
                bf16x8 av0 = *(const bf16x8*)(aB);
                bf16x8 av1 = *(const bf16x8*)(aB + 512);
                bf16x8 av2 = *(const bf16x8*)(aB + 1024);
                bf16x8 av3 = *(const bf16x8*)(aB + 1536);
                const char* pbase = ldsb + bbb + cii*(8*CIB);   // this wave's ci row

                #define RDBB(MM) union { uint32_t u_[4]; bf16x8 v; } bb; { \
                    const char* pp = pbase + ((MM) << 5); \
                    bb.u_[0] = *(const uint32_t*)(pp); \
                    bb.u_[1] = *(const uint32_t*)(pp + 4); \
                    bb.u_[2] = *(const uint32_t*)(pp + 8); \
                    bb.u_[3] = *(const uint32_t*)(pp + 12); }

                { RDBB(0) acc0 = __builtin_amdgcn_mfma_f32_32x32x16_bf16(av0, bb.v, acc0, 0,0,0); }
                { RDBB(1) acc0 = __builtin_amdgcn_mfma_f32_32x32x16_bf16(av1, bb.v, acc0, 0,0,0); }
                { RDBB(2) acc0 = __builtin_amdgcn_mfma_f32_32x32x16_bf16(av2, bb.v, acc0, 0,0,0);
                          acc1 = __builtin_amdgcn_mfma_f32_32x32x16_bf16(av0, bb.v, acc1, 0,0,0); }
                { RDBB(3) acc0 = __builtin_amdgcn_mfma_f32_32x32x16_bf16(av3, bb.v, acc0, 0,0,0);
                          acc1 = __builtin_amdgcn_mfma_f32_32x32x16_bf16(av1, bb.v, acc1, 0,0,0); }
                { RDBB(4) acc1 = __builtin_amdgcn_mfma_f32_32x32x16_bf16(av2, bb.v, acc1, 0,0,0);
                  if (full) acc2 = __builtin_amdgcn_mfma_f32_32x32x16_bf16(av0, bb.v, acc2, 0,0,0); }
                { RDBB(5) acc1 = __builtin_amdgcn_mfma_f32_32x32x16_bf16(av3, bb.v, acc1, 0,0,0);
                  if (full) acc2 = __builtin_amdgcn_mfma_f32_32x32x16_bf16(av1, bb.v, acc2, 0,0,0); }
                if (full) {
                    { RDBB(6) acc2 = __builtin_amdgcn_mfma_f32_32x32x16_bf16(av2, bb.v, acc2, 0,0,0);
                              acc3 = __builtin_amdgcn_mfma_f32_32x32x16_bf16(av0, bb.v, acc3, 0,0,0); }
                    { RDBB(7) acc2 = __builtin_amdgcn_mfma_f32_32x32x16_bf16(av3, bb.v, acc2, 0,0,0);
                              acc3 = __builtin_amdgcn_mfma_f32_32x32x16_bf16(av1, bb.v, acc3, 0,0,0); }
                    { RDBB(8) acc3 = __builtin_amdgcn_mfma_f32_32x32x16_bf16(av2, bb.v, acc3, 0,0,0); }
                    { RDBB(9) acc3 = __builtin_amdgcn_mfma_f32_32x32x16_bf16(av3, bb.v, acc3, 0,0,0); }
                }
                #undef RDBB
            }
        }

        // ---- reduce across 8 ci-waves + epilogue, one delta at a time ----
        float* red = (float*)lds4;           // 16 KB area (within staged region)
        #pragma unroll
        for (int dlt = 0; dlt < 4; ++dlt) {
            f32x16 a = (dlt == 0) ? acc0 : (dlt == 1) ? acc1 : (dlt == 2) ? acc2 : acc3;
            __syncthreads();                 // prior use of red / staged done
            if (w < 4) {
                #pragma unroll
                for (int r = 0; r < 16; ++r)
                    red[(w*16 + r)*64 + lane] = a[r];
            }
            __syncthreads();
            if (w >= 4) {
                #pragma unroll
                for (int r = 0; r < 16; ++r)
                    red[((w-4)*16 + r)*64 + lane] += a[r];
            }
            __syncthreads();
            int t0 = (th - dlt) << 5;
            #pragma unroll
            for (int h = 0; h < 2; ++h) {
                int e = tid + (h << 9);
                int lane_e = e & 63;
                int reg = e >> 6;
                float s = 0.f;
                #pragma unroll
                for (int ww = 0; ww < 4; ++ww) s += red[(ww*16 + reg)*64 + lane_e];
                int co = (reg & 3) + ((reg >> 2) << 3) + ((lane_e >> 5) << 2);
                int t = t0 + (lane_e & 31);
                out[(b*NCO + co)*T + t] = s + bias[co];
            }
        }
        __syncthreads();
    }
}

extern "C" void kernel_launch(void* const* d_in, const int* in_sizes, int n_in,
                              void* d_out, int out_size, void* d_ws, size_t ws_size,
                              hipStream_t stream)
{
    const float* x       = (const float*)d_in[0];
    const float* rel_pos = (const float*)d_in[1];
    const float* w1  = (const float*)d_in[2];
    const float* b1  = (const float*)d_in[3];
    const float* om1 = (const float*)d_in[4];
    const float* w2  = (const float*)d_in[5];
    const float* b2  = (const float*)d_in[6];
    const float* om2 = (const float*)d_in[7];
    const float* w3  = (const float*)d_in[8];
    const float* b3  = (const float*)d_in[9];
    const float* bias = (const float*)d_in[10];
    float* out = (float*)d_out;
    char* ws = (char*)d_ws;
    uint16_t* Wt  = (uint16_t*)(ws + WT_OFF);
    uint16_t* xrp = (uint16_t*)(ws + XR_OFF);
    uint16_t* xrs = (uint16_t*)(ws + XRS_OFF);

    hipLaunchKernelGGL(gen_w, dim3(WT_CH*8), dim3(256), 0, stream,
                       rel_pos, w1, b1, om1, w2, b2, om2, w3, b3, Wt);
    int n2 = NB*NCI*GR;
    hipLaunchKernelGGL(gen_x, dim3((n2+255)/256), dim3(256), 0, stream, x, xrp, xrs);
    hipLaunchKernelGGL(conv, dim3(NB*8), dim3(512), 0, stream, Wt, xrp, xrs, bias, out);
}